// Round 5
// baseline (8476.188 us; speedup 1.0000x reference)
//
#include <hip/hip_runtime.h>
#include <hip/hip_bf16.h>
#include <math.h>

#define BB 512
#define HH 512
#define TT 1024

typedef __bf16 bf16;
typedef __bf16 bf16x8 __attribute__((ext_vector_type(8)));
typedef float f32x4 __attribute__((ext_vector_type(4)));
typedef unsigned long long ull;

#define SENT 0x7FC07FC07FC07FC0ULL   // 4x bf16 NaN — h = so*tanh(c) is never NaN

// ---------------- ws layout (bytes) ----------------
// WcT  : [2048][512] bf16  @ 0       (2 MB)   folded: Whh + Wfc ⊗ Wih
// biasC: [2048] f32        @ 2 MB    (8 KB)
// hb0/1/2: [512][512] bf16 @ +8 KB   (3 x 512 KB) rotating A_s buffers
#define WT_OFF    0
#define BC_OFF    (2*1024*1024)
#define H0_OFF    (BC_OFF + 8192)
#define H1_OFF    (H0_OFF + 512*1024)
#define H2_OFF    (H1_OFF + 512*1024)

__global__ void prep_weights(const float* __restrict__ Whh, const float* __restrict__ Wih,
                             const float* __restrict__ bih, const float* __restrict__ bhh,
                             const float* __restrict__ Wfc, const float* __restrict__ bfc,
                             bf16* __restrict__ WcT, float* __restrict__ biasC) {
    int col = blockIdx.x;                 // 0..2047
    float wih = Wih[col];
    for (int k = threadIdx.x; k < HH; k += blockDim.x)
        WcT[col * HH + k] = (bf16)(Whh[col * HH + k] + Wfc[k] * wih);
    if (threadIdx.x == 0) biasC[col] = bih[col] + bhh[col] + bfc[0] * wih;
}

__global__ void prep_state(const float* __restrict__ h, bf16* __restrict__ h0buf,
                           unsigned short* __restrict__ h1buf,
                           unsigned short* __restrict__ h2buf) {
    int i = blockIdx.x * blockDim.x + threadIdx.x;
    if (i < BB * HH) {
        h0buf[i] = (bf16)h[i];
        h1buf[i] = 0x7FC0;    // sentinel
        h2buf[i] = 0x7FC0;
    }
}

__device__ __forceinline__ float tanh_fast(float x) {
    float ax = fabsf(x);
    float e = __expf(-2.f * ax);
    float r = (1.f - e) / (1.f + e);
    return copysignf(r, x);
}
__device__ __forceinline__ float sigmoid_fast(float x) {
    return 1.f / (1.f + __expf(-x));
}
__device__ __forceinline__ bool has_sent(ull v) {
    // exact any-16-bit-lane == 0x7FC0 test
    ull y = v ^ SENT;
    return ((y - 0x0001000100010001ULL) & ~y & 0x8000800080008000ULL) != 0ULL;
}

// Persistent LSTM with data-as-signal sync: no flags, no RMW, no acquire/
// release. Consumers poll their own h granules for the NaN sentinel; valid
// data arrival IS the publish. 3 rotating buffers + clear-behind (iter s
// clears buf[(s+2)%3]); an explicit s_waitcnt vmcnt(0) before the h store
// orders clear -> data on the same granule. Pure dataflow => deadlock-free.
__global__ __launch_bounds__(256, 1) void lstm_persist(
    const bf16* __restrict__ WcT,     // [2048][512] bf16 (folded)
    const float* __restrict__ biasC,  // [2048]
    const float* __restrict__ Wih,    // [2048]
    const float* __restrict__ Wfc,    // [512]
    const float* __restrict__ bfc,    // [1]
    const float* __restrict__ c0,     // [512*512] f32
    ull* __restrict__ hq0, ull* __restrict__ hq1, ull* __restrict__ hq2,
    float* __restrict__ out)          // [512][1024]
{
    __shared__ __align__(16) bf16 Alds[32 * 512];  // XOR-swizzled h tile (32 KB)
    __shared__ float xls[32];                      // step-0 correction per row
    __shared__ float WfcLDS[512];
    __shared__ bf16 hrep[32][40];                  // h repack for coalesced stores

    const int tid  = threadIdx.x;
    const int wave = tid >> 6;
    const int lane = tid & 63;
    const int l15  = lane & 15;
    const int hi   = lane >> 4;
    // XCD swizzle (perf-only; correctness is placement-free)
    const int xcd = blockIdx.x & 7;
    const int ii  = blockIdx.x >> 3;
    const int bt  = xcd * 2 + (ii & 1);       // 0..15
    const int hs  = ii >> 1;                  // 0..15

    WfcLDS[tid] = Wfc[tid];
    WfcLDS[tid + 256] = Wfc[tid + 256];

    // ---- preload folded weights into registers ----
    bf16x8 breg[2][16];
    float biasr[2], wihr[2];
    #pragma unroll
    for (int nt = 0; nt < 2; ++nt) {
        int gcol = (nt * 2 + (l15 >> 3)) * HH + hs * 32 + wave * 8 + (l15 & 7);
        const bf16* wp = WcT + (size_t)gcol * HH + hi * 8;
        #pragma unroll
        for (int kk = 0; kk < 16; ++kk)
            breg[nt][kk] = *(const bf16x8*)(wp + kk * 32);
        biasr[nt] = biasC[gcol];
        wihr[nt]  = Wih[gcol];
    }
    const bool lo = (l15 < 8);
    float p0 = __shfl_xor(biasr[0], 8), p1 = __shfl_xor(biasr[1], 8);
    const float bI = lo ? biasr[0] : p0, bF = lo ? p0 : biasr[0];
    const float bG = lo ? biasr[1] : p1, bO = lo ? p1 : biasr[1];
    p0 = __shfl_xor(wihr[0], 8); p1 = __shfl_xor(wihr[1], 8);
    const float wI = lo ? wihr[0] : p0, wF = lo ? p0 : wihr[0];
    const float wG = lo ? wihr[1] : p1, wO = lo ? p1 : wihr[1];

    const int mymt = lo ? 0 : 1;
    const int jcol = wave * 8 + (l15 & 7);    // col within slice (0..31)
    const int jloc = hs * 32 + jcol;
    float creg[4];
    #pragma unroll
    for (int r = 0; r < 4; ++r) {
        int brow = bt * 32 + mymt * 16 + hi * 4 + r;
        creg[r] = c0[(size_t)brow * HH + jloc];
    }
    const float bfcv = bfc[0];

    const int swz = l15 & 7;
    const int row = tid >> 3;                 // staging row 0..31
    const int seg = tid & 7;
    const int r7  = row & 7;
    const size_t srcbase = ((size_t)(bt * 32 + row)) * 128;        // ull units
    const size_t dstoff  = srcbase + hs * 8 + seg;

    // rotating buffer pointers: bA = buf[s%3] (read), bB = buf[(s+1)%3]
    // (write A_{s+1}), bC = buf[(s+2)%3] (clear for reuse at s+2)
    ull* bA = hq0; ull* bB = hq1; ull* bC = hq2;

    __syncthreads();   // WfcLDS ready

    for (int s = 0; s <= TT; ++s) {
        if (s == TT && hs != 0) break;      // only hs==0 needs the final tile

        // 1. stage A_s tile [32 x 512]: poll own granules until non-sentinel
        {
            const ull* srcq = bA + srcbase;
            unsigned pend = 0xFFu;
            ull q[16];
            while (pend) {
                #pragma unroll
                for (int u = 0; u < 8; ++u) {
                    if (pend & (1u << u)) {
                        const ull* p = srcq + 2 * (seg * 8 + u);
                        q[2*u]   = __hip_atomic_load(p,     __ATOMIC_RELAXED, __HIP_MEMORY_SCOPE_SYSTEM);
                        q[2*u+1] = __hip_atomic_load(p + 1, __ATOMIC_RELAXED, __HIP_MEMORY_SCOPE_SYSTEM);
                    }
                }
                unsigned np = 0;
                #pragma unroll
                for (int u = 0; u < 8; ++u) {
                    if (pend & (1u << u)) {
                        if (has_sent(q[2*u]) | has_sent(q[2*u+1])) {
                            np |= 1u << u;
                        } else {
                            int c = seg * 8 + u;
                            ull* dst = (ull*)(Alds + row * 512 + ((c ^ r7) << 3));
                            dst[0] = q[2*u];
                            dst[1] = q[2*u+1];
                        }
                    }
                }
                pend = np;
                if (pend) __builtin_amdgcn_s_sleep(1);
            }
        }
        __syncthreads();   // full A_s staged => whole group finished iter s-1

        // 2. clear-behind: sentinel my write-granule in buf[(s+2)%3]
        //    (safe: barrier above proves all group members read A_{s-1})
        __hip_atomic_store(bC + dstoff, SENT, __ATOMIC_RELAXED, __HIP_MEMORY_SCOPE_SYSTEM);

        // 3. FC: step-0 correction (all wgs) and/or y-output (hs==0)
        if (s == 0 || hs == 0) {
            float xacc = 0.f;
            const bf16* arow = Alds + row * 512;
            #pragma unroll
            for (int u = 0; u < 8; ++u) {
                int cc = seg * 8 + u;
                bf16x8 v = *(const bf16x8*)(arow + ((cc ^ r7) << 3));
                const float* wv = WfcLDS + cc * 8;
                #pragma unroll
                for (int e = 0; e < 8; ++e) xacc += (float)v[e] * wv[e];
            }
            xacc += __shfl_xor(xacc, 1);
            xacc += __shfl_xor(xacc, 2);
            xacc += __shfl_xor(xacc, 4);
            xacc += bfcv;
            if (seg == 0) {
                xls[row] = xacc;
                if (hs == 0 && s > 0)
                    out[((size_t)(bt * 32 + row)) * TT + (s - 1)] = xacc;
            }
        }

        if (s == TT) break;                 // epilogue done (y[TT-1] emitted)

        // 4. MFMA: [32,512] @ [512, 32 B-rows]; A from swizzled LDS, B from regs
        f32x4 acc[2][2];
        #pragma unroll
        for (int i = 0; i < 2; ++i)
            #pragma unroll
            for (int j = 0; j < 2; ++j) acc[i][j] = (f32x4)0.f;

        #pragma unroll
        for (int kk = 0; kk < 16; ++kk) {
            int ch = ((hi + 4 * kk) ^ swz) << 3;
            bf16x8 a0 = *(const bf16x8*)(Alds + l15 * 512 + ch);
            bf16x8 a1 = *(const bf16x8*)(Alds + (l15 + 16) * 512 + ch);
            acc[0][0] = __builtin_amdgcn_mfma_f32_16x16x32_bf16(a0, breg[0][kk], acc[0][0], 0, 0, 0);
            acc[0][1] = __builtin_amdgcn_mfma_f32_16x16x32_bf16(a0, breg[1][kk], acc[0][1], 0, 0, 0);
            acc[1][0] = __builtin_amdgcn_mfma_f32_16x16x32_bf16(a1, breg[0][kk], acc[1][0], 0, 0, 0);
            acc[1][1] = __builtin_amdgcn_mfma_f32_16x16x32_bf16(a1, breg[1][kk], acc[1][1], 0, 0, 0);
        }

        if (s == 0) __syncthreads();   // xls visible for the correction

        // 5. pointwise cell update (folded weights include x-feedback;
        //    s==0 subtracts the x0c*Wih correction since x_0 = 0)
        #pragma unroll
        for (int r = 0; r < 4; ++r) {
            float send0 = lo ? acc[1][0][r] : acc[0][0][r];
            float send1 = lo ? acc[1][1][r] : acc[0][1][r];
            float recv0 = __shfl_xor(send0, 8);
            float recv1 = __shfl_xor(send1, 8);
            float own0  = lo ? acc[0][0][r] : acc[1][0][r];
            float own1  = lo ? acc[0][1][r] : acc[1][1][r];
            int  lrow = mymt * 16 + hi * 4 + r;
            float xc = (s == 0) ? xls[lrow] : 0.f;
            float xi = (lo ? own0 : recv0) + bI - xc * wI;
            float xf = (lo ? recv0 : own0) + bF - xc * wF;
            float xg = (lo ? own1 : recv1) + bG - xc * wG;
            float xo = (lo ? recv1 : own1) + bO - xc * wO;
            float si = sigmoid_fast(xi), sf = sigmoid_fast(xf), so = sigmoid_fast(xo);
            float tg = tanh_fast(xg);
            float cn = sf * creg[r] + si * tg;
            creg[r] = cn;
            hrep[lrow][jcol] = (bf16)(so * tanh_fast(cn));
        }
        __syncthreads();   // hrep complete; Alds reads finished

        // 6. store A_{s+1} granule. The vmcnt(0) fence guarantees my earlier
        //    sentinel-clear of this same granule (iter s-1) reached MALL
        //    before this data store issues (same thread, same address).
        {
            ull val = *(const ull*)&hrep[row][seg * 4];
            asm volatile("s_waitcnt vmcnt(0)" ::: "memory");
            __hip_atomic_store(bB + dstoff, val, __ATOMIC_RELAXED, __HIP_MEMORY_SCOPE_SYSTEM);
        }

        // rotate buffers: (A,B,C) <- (B,C,A)
        ull* t = bA; bA = bB; bB = bC; bC = t;
    }
}

extern "C" void kernel_launch(void* const* d_in, const int* in_sizes, int n_in,
                              void* d_out, int out_size, void* d_ws, size_t ws_size,
                              hipStream_t stream) {
    const float* h   = (const float*)d_in[0];
    const float* c   = (const float*)d_in[1];
    const float* Wih = (const float*)d_in[2];
    const float* Whh = (const float*)d_in[3];
    const float* bih = (const float*)d_in[4];
    const float* bhh = (const float*)d_in[5];
    const float* Wfc = (const float*)d_in[6];
    const float* bfc = (const float*)d_in[7];
    float* out = (float*)d_out;

    char* ws = (char*)d_ws;
    bf16*  WcT   = (bf16*)(ws + WT_OFF);
    float* biasC = (float*)(ws + BC_OFF);
    bf16*  hb0   = (bf16*)(ws + H0_OFF);
    unsigned short* hb1 = (unsigned short*)(ws + H1_OFF);
    unsigned short* hb2 = (unsigned short*)(ws + H2_OFF);

    prep_weights<<<2048, 256, 0, stream>>>(Whh, Wih, bih, bhh, Wfc, bfc, WcT, biasC);
    prep_state<<<1024, 256, 0, stream>>>(h, hb0, hb1, hb2);
    lstm_persist<<<256, 256, 0, stream>>>(WcT, biasC, Wih, Wfc, bfc, c,
                                          (ull*)(ws + H0_OFF), (ull*)(ws + H1_OFF),
                                          (ull*)(ws + H2_OFF), out);
}